// Round 9
// baseline (320.005 us; speedup 1.0000x reference)
//
#include <hip/hip_runtime.h>
#include <math.h>

#define NN   10000
#define EE   200000
#define RR   400000
#define FIN  128
#define FOUT 64

#define HASH_BITS 20
#define HSIZE (1u << HASH_BITS)
#define HMASK (HSIZE - 1u)
#define ROWCAP 256           // per-row edge slots (Poisson(40): P(>256)~0)

#define NKB 314              // k-blocks of 32 covering 10048
#define LDB 264              // LDS tile row stride in bf16 (256+8): 528B=132 words -> 2-way free

typedef __bf16 bf16x8 __attribute__((ext_vector_type(8)));
typedef __bf16 bf16x4 __attribute__((ext_vector_type(4)));
typedef float  f32x4  __attribute__((ext_vector_type(4)));

// ---- workspace layout (units of 4 bytes) ----
#define O_SUMS   0
#define O_CNTS   (O_SUMS + EE)
#define O_ROWCNT (O_CNTS + EE)             // int[NN]
#define O_HKEY   (O_ROWCNT + NN)
#define O_HPRIO  (O_HKEY + HSIZE)
#define O_SEQTP  (O_HPRIO + HSIZE)         // packed bf16 [NKB][5][64][8]
#define SEQTP_WORDS (NKB * 5 * 512 / 2)    // 401920
#define ZERO_WORDS (O_SEQTP + SEQTP_WORDS) // 2909072 (div by 4)
#define O_NUMP   ZERO_WORDS                // f32[8][NN][64]
#define O_SP     (O_NUMP + 8 * NN * FOUT)  // f32[8][NN]
#define O_PAIRS  (O_SP + 8 * NN)           // uint2[NN][ROWCAP]

// ---------------- wide zero fill ----------------
__global__ __launch_bounds__(256) void k_zero(f32x4* __restrict__ p, int n4) {
    int gid = blockIdx.x * 256 + threadIdx.x;
    if (gid < n4) p[gid] = (f32x4){0.f, 0.f, 0.f, 0.f};
}

// -------- seq_fts = x @ W^T, emitted as MFMA-fragment-packed bf16 ----------
// packed value(kb, n, lane, slot) = seq[col = n*16+(lane&15)][k = kb*32+(lane>>4)*8+slot]
// n==4 is the all-ones fragment (row-sum via MFMA).
__global__ __launch_bounds__(256) void k_seqfts(const float* __restrict__ x,
                                                const float* __restrict__ W,
                                                __bf16* __restrict__ seqTp) {
    __shared__ float Wt[FIN][FOUT + 1];
    __shared__ float xs[FIN][16 + 1];
    int t = threadIdx.x;
    for (int e = t; e < FOUT * FIN; e += 256) {
        int c = e >> 7, k = e & 127;
        Wt[k][c] = W[e];
    }
    int row0 = blockIdx.x * 16;
    for (int e = t; e < 16 * FIN; e += 256) {
        int r = e >> 7, k = e & 127;
        int gr = row0 + r;
        xs[k][r] = (gr < NN) ? x[(size_t)gr * FIN + k] : 0.f;
    }
    __syncthreads();
    int col = t & 63;
    int rg  = t >> 6;
    float acc[4] = {0.f, 0.f, 0.f, 0.f};
    for (int k = 0; k < FIN; ++k) {
        float w = Wt[k][col];
        #pragma unroll
        for (int i = 0; i < 4; ++i) acc[i] += w * xs[k][rg * 4 + i];
    }
    #pragma unroll
    for (int i = 0; i < 4; ++i) {
        int gr = row0 + rg * 4 + i;          // gr = K index, always < NN here
        int kb = gr >> 5, g = (gr >> 3) & 3, slot = gr & 7;
        seqTp[((size_t)kb * 5 + (col >> 4)) * 512 + ((col & 15) + g * 16) * 8 + slot]
            = (__bf16)acc[i];
        if (col < 16)
            seqTp[((size_t)kb * 5 + 4) * 512 + (col + g * 16) * 8 + slot] = (__bf16)1.0f;
    }
}

// ---------------- helpers ----------------
__device__ __forceinline__ unsigned hash_cell(unsigned cell) {
    return (cell * 2654435761u) >> (32 - HASH_BITS);
}
__device__ __forceinline__ void entry_ij(const int* ep, int e, int& i, int& j, int& k) {
    k = (e < EE) ? e : e - EE;
    int a = ep[2 * k], b = ep[2 * k + 1];
    if (e < EE) { i = a; j = b; } else { i = b; j = a; }
}

// ------- merged (wave roles, no barriers): main matmul || rel || hash ------
#define KSPLIT 8
#define NSTRIP (NN / 16)                 // 625
#define CPW 5                            // chunks per wave (40 chunks / 8 splits)
#define CHK 256                          // chunk K width
#define MAINW (NSTRIP * KSPLIT)          // 5000
#define RELW  (RR / 16)                  // 25000
#define HASHW ((2 * EE + 63) / 64)       // 6250
#define TOTW  (MAINW + RELW + HASHW)     // 36250
#define GRID_MR ((TOTW + 3) / 4)         // 9063

__global__ __launch_bounds__(256, 4) void k_mainrel(const float* __restrict__ adj,
                                                    const __bf16* __restrict__ seqTp,
                                                    const float* __restrict__ rel,
                                                    const float* __restrict__ wrel,
                                                    const int* __restrict__ rseg,
                                                    const int* __restrict__ ep,
                                                    float* __restrict__ sums,
                                                    float* __restrict__ cnts,
                                                    unsigned* __restrict__ hkey,
                                                    unsigned* __restrict__ hprio,
                                                    float* __restrict__ Nump,
                                                    float* __restrict__ Sp) {
    __shared__ __bf16 atile[4][16 * LDB];   // per-wave private 16x256 bf16 tile
    int t   = threadIdx.x;
    int wid = blockIdx.x * 4 + (t >> 6);
    int l   = t & 63;

    if (wid < MAINW) {
        int strip = wid >> 3;            // [0,625)
        int ks    = wid & 7;
        int row0  = strip * 16;
        int lr = l & 15, lk = l >> 4;
        __bf16* my = &atile[t >> 6][0];

        f32x4 acc[5];
        #pragma unroll
        for (int n = 0; n < 5; ++n) acc[n] = (f32x4){0.f, 0.f, 0.f, 0.f};

        f32x4 pv[16];
        int c0 = ks * CPW;

        // prologue: contiguous 1KB-per-instruction row loads (lane l -> cols 4l..4l+3)
        {
            int k0 = c0 * CHK;
            bool ok = (k0 + 4 * l) < NN;   // always true in prologue (k0<=8960)
            #pragma unroll
            for (int r = 0; r < 16; ++r) {
                f32x4 v = (f32x4){-1e9f, -1e9f, -1e9f, -1e9f};
                if (ok) v = *(const f32x4*)(adj + (size_t)(row0 + r) * NN + k0 + 4 * l);
                pv[r] = v;
            }
        }

        #pragma unroll
        for (int c = 0; c < CPW; ++c) {
            int k0 = (c0 + c) * CHK;
            // stage: exp + bf16 pack + per-wave LDS write (row-contig, conflict-free)
            #pragma unroll
            for (int r = 0; r < 16; ++r) {
                float e0 = exp2f(fmaf(pv[r].x, 1.442695041f, 0.7213475204f));
                float e1 = exp2f(fmaf(pv[r].y, 1.442695041f, 0.7213475204f));
                float e2 = exp2f(fmaf(pv[r].z, 1.442695041f, 0.7213475204f));
                float e3 = exp2f(fmaf(pv[r].w, 1.442695041f, 0.7213475204f));
                bf16x4 q = { (__bf16)e0, (__bf16)e1, (__bf16)e2, (__bf16)e3 };
                *(bf16x4*)&my[r * LDB + l * 4] = q;
            }
            // prefetch next chunk (HBM latency hides under MFMA phase below)
            if (c + 1 < CPW) {
                int kn = (c0 + c + 1) * CHK;
                bool ok = (kn + 4 * l) < NN;
                #pragma unroll
                for (int r = 0; r < 16; ++r) {
                    f32x4 v = (f32x4){-1e9f, -1e9f, -1e9f, -1e9f};
                    if (ok) v = *(const f32x4*)(adj + (size_t)(row0 + r) * NN + kn + 4 * l);
                    pv[r] = v;
                }
            }
            // compute: A-frag from own LDS, B-frag = contiguous 1KB L2 load
            int kb0  = k0 >> 5;
            int hmax = min(8, (NN - k0 + 31) >> 5);
            for (int h = 0; h < hmax; ++h) {
                bf16x8 af = *(const bf16x8*)&my[lr * LDB + lk * 8 + h * 32];
                const __bf16* bp = seqTp + (size_t)(kb0 + h) * 5 * 512 + l * 8;
                #pragma unroll
                for (int n = 0; n < 5; ++n) {
                    bf16x8 b = *(const bf16x8*)(bp + n * 512);
                    acc[n] = __builtin_amdgcn_mfma_f32_16x16x32_bf16(af, b, acc[n], 0, 0, 0);
                }
            }
        }

        // C/D layout: col = lane&15, row = (lane>>4)*4 + reg
        float* nout = Nump + (size_t)ks * NN * FOUT;
        #pragma unroll
        for (int n = 0; n < 4; ++n) {
            #pragma unroll
            for (int r = 0; r < 4; ++r)
                nout[(size_t)(row0 + lk * 4 + r) * FOUT + n * 16 + lr] = acc[n][r];
        }
        if (lr == 0) {                      // ones-fragment -> f32 row sums
            #pragma unroll
            for (int r = 0; r < 4; ++r)
                Sp[(size_t)ks * NN + row0 + lk * 4 + r] = acc[4][r];
        }
        return;
    }

    if (wid < MAINW + RELW) {
        // ---- rel role: 16 rows per wave, 32-lane group per row ----
        int rw   = wid - MAINW;
        int lane = l & 31;
        int half = l >> 5;
        f32x4 wv = *(const f32x4*)(wrel + lane * 4);
        #pragma unroll
        for (int it = 0; it < 8; ++it) {
            int row = rw * 16 + it * 2 + half;   // RELW*16 == RR exactly
            f32x4 v = *(const f32x4*)(rel + (size_t)row * FIN + lane * 4);
            float s = v.x * wv.x + v.y * wv.y + v.z * wv.z + v.w * wv.w;
            #pragma unroll
            for (int off = 16; off >= 1; off >>= 1) s += __shfl_xor(s, off, 64);
            if (lane == 0) {
                int seg = rseg[row];
                atomicAdd(&sums[seg], s);
                atomicAdd(&cnts[seg], 1.0f);
            }
        }
        return;
    }

    // ---- hash-build role ----
    {
        int e = (wid - MAINW - RELW) * 64 + l;
        if (e >= 2 * EE) return;
        int i, j, k;
        entry_ij(ep, e, i, j, k);
        unsigned cell = (unsigned)i * NN + (unsigned)j;
        unsigned keyv = cell + 1u;
        unsigned h = hash_cell(cell);
        while (true) {
            unsigned old = atomicCAS(&hkey[h], 0u, keyv);
            if (old == 0u || old == keyv) break;
            h = (h + 1u) & HMASK;
        }
        atomicMax(&hprio[h], (unsigned)(e + 1));
    }
}

// ------- scatB: winner check + dw compute + push (j,dw) into row bucket -----
__global__ __launch_bounds__(256) void k_scatB(const int* __restrict__ ep,
                                               const float* __restrict__ sums,
                                               const float* __restrict__ cnts,
                                               const unsigned* __restrict__ hkey,
                                               const unsigned* __restrict__ hprio,
                                               const float* __restrict__ adj,
                                               int* __restrict__ rowcnt,
                                               uint2* __restrict__ pairs) {
    int e = blockIdx.x * 256 + threadIdx.x;
    if (e >= 2 * EE) return;
    int i, j, k;
    entry_ij(ep, e, i, j, k);
    unsigned cell = (unsigned)i * NN + (unsigned)j;
    unsigned keyv = cell + 1u;
    unsigned h = hash_cell(cell);
    while (hkey[h] != keyv) h = (h + 1u) & HMASK;
    if (hprio[h] == (unsigned)(e + 1)) {   // last-write-wins winner
        float v   = sums[k] / fmaxf(cnts[k], 1.0f);
        float sg  = 1.f / (1.f + __expf(-v));
        float aij = adj[(size_t)i * NN + j];
        float dw  = __expf(aij + sg) - __expf(aij + 0.5f);
        if (dw != 0.f) {
            int pos = atomicAdd(&rowcnt[i], 1);
            if (pos < ROWCAP)
                pairs[(size_t)i * ROWCAP + pos] =
                    make_uint2((unsigned)j, __float_as_uint(dw));
        }
    }
}

// ------- rowupd: one wave per row: sum partials + edge corr + elu -> out ----
__global__ __launch_bounds__(256) void k_rowupd(const float* __restrict__ Nump,
                                                const float* __restrict__ Sp,
                                                const int* __restrict__ rowcnt,
                                                const uint2* __restrict__ pairs,
                                                const __bf16* __restrict__ seqTp,
                                                const float* __restrict__ bias,
                                                float* __restrict__ out) {
    int t = threadIdx.x;
    int i = blockIdx.x * 4 + (t >> 6);
    if (i >= NN) return;
    int c = t & 63;
    float acc = 0.f, sb = 0.f;
    #pragma unroll
    for (int ks = 0; ks < 8; ++ks) {
        acc += Nump[(size_t)ks * NN * FOUT + (size_t)i * FOUT + c];
        sb  += Sp[(size_t)ks * NN + i];
    }
    int cnt = min(rowcnt[i], ROWCAP);
    float sdw = 0.f;
    const uint2* pr = pairs + (size_t)i * ROWCAP;
    for (int e = 0; e < cnt; ++e) {
        uint2 pk = pr[e];                      // wave-uniform broadcast load
        float d  = __uint_as_float(pk.y);
        unsigned j = pk.x;
        float sj = (float)seqTp[((size_t)(j >> 5) * 5 + (c >> 4)) * 512
                                + ((c & 15) + ((j >> 3) & 3) * 16) * 8 + (j & 7)];
        acc += d * sj;
        sdw += d;
    }
    float v = acc / (sb + sdw) + bias[c];
    out[(size_t)i * FOUT + c] = (v > 0.f) ? v : expm1f(v);
}

extern "C" void kernel_launch(void* const* d_in, const int* in_sizes, int n_in,
                              void* d_out, int out_size, void* d_ws, size_t ws_size,
                              hipStream_t stream) {
    const float* x    = (const float*)d_in[0];
    const float* rel  = (const float*)d_in[1];
    const float* adj  = (const float*)d_in[2];
    const int*   ep   = (const int*)d_in[3];
    const int*   rseg = (const int*)d_in[4];
    const float* W    = (const float*)d_in[5];
    const float* wrel = (const float*)d_in[6];
    const float* bias = (const float*)d_in[7];
    float* out = (float*)d_out;

    float* ws = (float*)d_ws;
    float*    sums   = ws + O_SUMS;
    float*    cnts   = ws + O_CNTS;
    int*      rowcnt = (int*)(ws + O_ROWCNT);
    unsigned* hkey   = (unsigned*)(ws + O_HKEY);
    unsigned* hprio  = (unsigned*)(ws + O_HPRIO);
    __bf16*   seqTp  = (__bf16*)(ws + O_SEQTP);
    float*    Nump   = ws + O_NUMP;
    float*    Sp     = ws + O_SP;
    uint2*    pairs  = (uint2*)(ws + O_PAIRS);

    int n4 = ZERO_WORDS / 4;
    k_zero<<<(n4 + 255) / 256, 256, 0, stream>>>((f32x4*)d_ws, n4);
    k_seqfts<<<NN / 16, 256, 0, stream>>>(x, W, seqTp);
    k_mainrel<<<GRID_MR, 256, 0, stream>>>(adj, seqTp, rel, wrel, rseg, ep,
                                           sums, cnts, hkey, hprio, Nump, Sp);
    k_scatB<<<(2 * EE + 255) / 256, 256, 0, stream>>>(ep, sums, cnts, hkey, hprio,
                                                      adj, rowcnt, pairs);
    k_rowupd<<<(NN + 3) / 4, 256, 0, stream>>>(Nump, Sp, rowcnt, pairs,
                                               seqTp, bias, out);
}

// Round 10
// 315.612 us; speedup vs baseline: 1.0139x; 1.0139x over previous
//
#include <hip/hip_runtime.h>
#include <math.h>

#define NN   10000
#define EE   200000
#define RR   400000
#define FIN  128
#define FOUT 64

#define HASH_BITS 20
#define HSIZE (1u << HASH_BITS)
#define HMASK (HSIZE - 1u)
#define ROWCAP 256           // per-row edge slots (Poisson(40): P(>256)~0)

#define NKB 314              // k-blocks of 32 covering 10048
#define NC  20               // K chunks of 512 f32
#define CHKF 512
#define LDSP 520             // bf16 row stride in LDS tile

typedef __bf16 bf16x8 __attribute__((ext_vector_type(8)));
typedef __bf16 bf16x4 __attribute__((ext_vector_type(4)));
typedef float  f32x4  __attribute__((ext_vector_type(4)));

// ---- workspace layout (units of 4 bytes) ----
#define O_SUMS   0
#define O_CNTS   (O_SUMS + EE)
#define O_ROWCNT (O_CNTS + EE)             // int[NN]
#define O_HKEY   (O_ROWCNT + NN)
#define O_HPRIO  (O_HKEY + HSIZE)
#define O_SEQTP  (O_HPRIO + HSIZE)         // packed bf16 [NKB][5][64][8]
#define SEQTP_WORDS (NKB * 5 * 512 / 2)
#define ZERO_WORDS (O_SEQTP + SEQTP_WORDS) // div by 4
#define O_NUMP   ZERO_WORDS                // f32[4][NN][64]
#define O_SP     (O_NUMP + 4 * NN * FOUT)  // f32[4][NN]
#define O_PAIRS  (O_SP + 4 * NN)           // uint2[NN][ROWCAP]

// ---------------- wide zero fill ----------------
__global__ __launch_bounds__(256) void k_zero(f32x4* __restrict__ p, int n4) {
    int gid = blockIdx.x * 256 + threadIdx.x;
    if (gid < n4) p[gid] = (f32x4){0.f, 0.f, 0.f, 0.f};
}

// -------- seq_fts = x @ W^T, emitted as MFMA-fragment-packed bf16 ----------
// packed(kb, n, lane, slot) = seq[col = n*16+(lane&15)][k = kb*32+(lane>>4)*8+slot]
// n==4 is the all-ones fragment (row-sum via MFMA).
__global__ __launch_bounds__(256) void k_seqfts(const float* __restrict__ x,
                                                const float* __restrict__ W,
                                                __bf16* __restrict__ seqTp) {
    __shared__ float Wt[FIN][FOUT + 1];
    __shared__ float xs[FIN][16 + 1];
    int t = threadIdx.x;
    for (int e = t; e < FOUT * FIN; e += 256) {
        int c = e >> 7, k = e & 127;
        Wt[k][c] = W[e];
    }
    int row0 = blockIdx.x * 16;
    for (int e = t; e < 16 * FIN; e += 256) {
        int r = e >> 7, k = e & 127;
        int gr = row0 + r;
        xs[k][r] = (gr < NN) ? x[(size_t)gr * FIN + k] : 0.f;
    }
    __syncthreads();
    int col = t & 63;
    int rg  = t >> 6;
    float acc[4] = {0.f, 0.f, 0.f, 0.f};
    for (int k = 0; k < FIN; ++k) {
        float w = Wt[k][col];
        #pragma unroll
        for (int i = 0; i < 4; ++i) acc[i] += w * xs[k][rg * 4 + i];
    }
    #pragma unroll
    for (int i = 0; i < 4; ++i) {
        int gr = row0 + rg * 4 + i;          // gr = K index, always < NN here
        int kb = gr >> 5, g = (gr >> 3) & 3, slot = gr & 7;
        seqTp[((size_t)kb * 5 + (col >> 4)) * 512 + ((col & 15) + g * 16) * 8 + slot]
            = (__bf16)acc[i];
        if (col < 16)
            seqTp[((size_t)kb * 5 + 4) * 512 + (col + g * 16) * 8 + slot] = (__bf16)1.0f;
    }
}

// ---------------- helpers ----------------
__device__ __forceinline__ unsigned hash_cell(unsigned cell) {
    return (cell * 2654435761u) >> (32 - HASH_BITS);
}
__device__ __forceinline__ void entry_ij(const int* ep, int e, int& i, int& j, int& k) {
    k = (e < EE) ? e : e - EE;
    int a = ep[2 * k], b = ep[2 * k + 1];
    if (e < EE) { i = a; j = b; } else { i = b; j = a; }
}

// ---------------- hash build (standalone) ----------------
__global__ __launch_bounds__(256) void k_hash(const int* __restrict__ ep,
                                              unsigned* __restrict__ hkey,
                                              unsigned* __restrict__ hprio) {
    int e = blockIdx.x * 256 + threadIdx.x;
    if (e >= 2 * EE) return;
    int i, j, k;
    entry_ij(ep, e, i, j, k);
    unsigned cell = (unsigned)i * NN + (unsigned)j;
    unsigned keyv = cell + 1u;
    unsigned h = hash_cell(cell);
    while (true) {
        unsigned old = atomicCAS(&hkey[h], 0u, keyv);
        if (old == 0u || old == keyv) break;
        h = (h + 1u) & HMASK;
    }
    atomicMax(&hprio[h], (unsigned)(e + 1));
}

// ---------------- rel segsum (standalone, compact sweeping front) ----------
#define RELBLK 2048
__global__ __launch_bounds__(256) void k_rel(const float* __restrict__ rel,
                                             const float* __restrict__ wrel,
                                             const int* __restrict__ rseg,
                                             float* __restrict__ sums,
                                             float* __restrict__ cnts) {
    int t = threadIdx.x;
    int wv = blockIdx.x * 4 + (t >> 6);    // wave id in [0, 8192)
    int l = t & 63;
    int lane = l & 31, half = l >> 5;
    f32x4 wvv = *(const f32x4*)(wrel + lane * 4);
    const int NW2 = RELBLK * 4 * 2;        // rows per sweep step (16384)
    for (int base = wv * 2; base < RR; base += NW2) {
        int row = base + half;             // RR even: row < RR guaranteed
        f32x4 v = *(const f32x4*)(rel + (size_t)row * FIN + lane * 4);
        float s = v.x * wvv.x + v.y * wvv.y + v.z * wvv.z + v.w * wvv.w;
        s += __shfl_xor(s, 1, 64);
        s += __shfl_xor(s, 2, 64);
        s += __shfl_xor(s, 4, 64);
        s += __shfl_xor(s, 8, 64);
        s += __shfl_xor(s, 16, 64);        // stays within each 32-half
        if (lane == 0) {
            int seg = rseg[row];
            atomicAdd(&sums[seg], s);
            atomicAdd(&cnts[seg], 1.0f);
        }
    }
}

// ---------------- main matmul: long forward-sequential row streams ---------
// 625 blocks x 16 rows; each wave streams 4 rows start-to-finish (40KB each).
// K-split across the block's 4 waves per chunk; 4 output partials.
__global__ __launch_bounds__(256) void k_main(const float* __restrict__ adj,
                                              const __bf16* __restrict__ seqTp,
                                              float* __restrict__ Nump,
                                              float* __restrict__ Sp) {
    __shared__ __bf16 As[2][16][LDSP];
    int t = threadIdx.x;
    int w = t >> 6, l = t & 63;
    int row0 = blockIdx.x * 16;
    int lr = l & 15, lk = l >> 4;

    f32x4 acc[5];
    #pragma unroll
    for (int n = 0; n < 5; ++n) acc[n] = (f32x4){0.f, 0.f, 0.f, 0.f};

    f32x4 pv[8];
    // prologue: chunk 0 (rows w*4..w*4+3, cols [0,512) — all in bounds)
    #pragma unroll
    for (int r = 0; r < 4; ++r) {
        const float* ap = adj + (size_t)(row0 + w * 4 + r) * NN;
        pv[2 * r]     = *(const f32x4*)(ap + 4 * l);
        pv[2 * r + 1] = *(const f32x4*)(ap + 256 + 4 * l);
    }

    int p = 0;
    for (int c = 0; c < NC; ++c) {
        // stage: exp + bf16 pack -> As[p] (wave writes its own 4 rows)
        #pragma unroll
        for (int r = 0; r < 4; ++r) {
            #pragma unroll
            for (int h2 = 0; h2 < 2; ++h2) {
                f32x4 v = pv[2 * r + h2];
                float e0 = exp2f(fmaf(v.x, 1.442695041f, 0.7213475204f));
                float e1 = exp2f(fmaf(v.y, 1.442695041f, 0.7213475204f));
                float e2 = exp2f(fmaf(v.z, 1.442695041f, 0.7213475204f));
                float e3 = exp2f(fmaf(v.w, 1.442695041f, 0.7213475204f));
                bf16x4 q = { (__bf16)e0, (__bf16)e1, (__bf16)e2, (__bf16)e3 };
                *(bf16x4*)&As[p][w * 4 + r][h2 * 256 + 4 * l] = q;
            }
        }
        // prefetch chunk c+1 (forward-sequential continuation of same rows)
        if (c + 1 < NC) {
            int kn = (c + 1) * CHKF;
            #pragma unroll
            for (int r = 0; r < 4; ++r) {
                const float* ap = adj + (size_t)(row0 + w * 4 + r) * NN + kn;
                pv[2 * r] = *(const f32x4*)(ap + 4 * l);        // kn+4l <= 9980: always ok
                int g1 = kn + 256 + 4 * l;
                pv[2 * r + 1] = (g1 < NN) ? *(const f32x4*)(ap + 256 + 4 * l)
                                          : (f32x4){-1e9f, -1e9f, -1e9f, -1e9f};
            }
        }
        __syncthreads();   // As[p] ready; dbuf => single barrier per chunk
        // MFMA: wave w covers K cols [w*128, w*128+128) of this chunk
        int kb0 = (c * CHKF) >> 5;
        #pragma unroll
        for (int h = 0; h < 4; ++h) {
            int kb = kb0 + w * 4 + h;
            if (kb < NKB) {
                bf16x8 af = *(const bf16x8*)&As[p][lr][w * 128 + h * 32 + lk * 8];
                const __bf16* bp = seqTp + (size_t)kb * 5 * 512 + l * 8;
                #pragma unroll
                for (int n = 0; n < 5; ++n) {
                    bf16x8 b = *(const bf16x8*)(bp + n * 512);
                    acc[n] = __builtin_amdgcn_mfma_f32_16x16x32_bf16(af, b, acc[n], 0, 0, 0);
                }
            }
        }
        p ^= 1;
    }

    // C/D layout: col = lane&15, row = (lane>>4)*4 + reg ; per-wave partial slot
    float* nout = Nump + (size_t)w * NN * FOUT;
    #pragma unroll
    for (int n = 0; n < 4; ++n) {
        #pragma unroll
        for (int r = 0; r < 4; ++r)
            nout[(size_t)(row0 + lk * 4 + r) * FOUT + n * 16 + lr] = acc[n][r];
    }
    if (lr == 0) {                      // ones-fragment -> f32 row sums
        #pragma unroll
        for (int r = 0; r < 4; ++r)
            Sp[(size_t)w * NN + row0 + lk * 4 + r] = acc[4][r];
    }
}

// ------- scatB: winner check + dw compute + push (j,dw) into row bucket -----
__global__ __launch_bounds__(256) void k_scatB(const int* __restrict__ ep,
                                               const float* __restrict__ sums,
                                               const float* __restrict__ cnts,
                                               const unsigned* __restrict__ hkey,
                                               const unsigned* __restrict__ hprio,
                                               const float* __restrict__ adj,
                                               int* __restrict__ rowcnt,
                                               uint2* __restrict__ pairs) {
    int e = blockIdx.x * 256 + threadIdx.x;
    if (e >= 2 * EE) return;
    int i, j, k;
    entry_ij(ep, e, i, j, k);
    unsigned cell = (unsigned)i * NN + (unsigned)j;
    unsigned keyv = cell + 1u;
    unsigned h = hash_cell(cell);
    while (hkey[h] != keyv) h = (h + 1u) & HMASK;
    if (hprio[h] == (unsigned)(e + 1)) {   // last-write-wins winner
        float v   = sums[k] / fmaxf(cnts[k], 1.0f);
        float sg  = 1.f / (1.f + __expf(-v));
        float aij = adj[(size_t)i * NN + j];
        float dw  = __expf(aij + sg) - __expf(aij + 0.5f);
        if (dw != 0.f) {
            int pos = atomicAdd(&rowcnt[i], 1);
            if (pos < ROWCAP)
                pairs[(size_t)i * ROWCAP + pos] =
                    make_uint2((unsigned)j, __float_as_uint(dw));
        }
    }
}

// ------- rowupd: one wave per row: sum partials + edge corr + elu -> out ----
__global__ __launch_bounds__(256) void k_rowupd(const float* __restrict__ Nump,
                                                const float* __restrict__ Sp,
                                                const int* __restrict__ rowcnt,
                                                const uint2* __restrict__ pairs,
                                                const __bf16* __restrict__ seqTp,
                                                const float* __restrict__ bias,
                                                float* __restrict__ out) {
    int t = threadIdx.x;
    int i = blockIdx.x * 4 + (t >> 6);
    if (i >= NN) return;
    int c = t & 63;
    float acc = 0.f, sb = 0.f;
    #pragma unroll
    for (int ks = 0; ks < 4; ++ks) {
        acc += Nump[(size_t)ks * NN * FOUT + (size_t)i * FOUT + c];
        sb  += Sp[(size_t)ks * NN + i];
    }
    int cnt = min(rowcnt[i], ROWCAP);
    float sdw = 0.f;
    const uint2* pr = pairs + (size_t)i * ROWCAP;
    for (int e = 0; e < cnt; ++e) {
        uint2 pk = pr[e];                      // wave-uniform broadcast load
        float d  = __uint_as_float(pk.y);
        unsigned j = pk.x;
        float sj = (float)seqTp[((size_t)(j >> 5) * 5 + (c >> 4)) * 512
                                + ((c & 15) + ((j >> 3) & 3) * 16) * 8 + (j & 7)];
        acc += d * sj;
        sdw += d;
    }
    float v = acc / (sb + sdw) + bias[c];
    out[(size_t)i * FOUT + c] = (v > 0.f) ? v : expm1f(v);
}

extern "C" void kernel_launch(void* const* d_in, const int* in_sizes, int n_in,
                              void* d_out, int out_size, void* d_ws, size_t ws_size,
                              hipStream_t stream) {
    const float* x    = (const float*)d_in[0];
    const float* rel  = (const float*)d_in[1];
    const float* adj  = (const float*)d_in[2];
    const int*   ep   = (const int*)d_in[3];
    const int*   rseg = (const int*)d_in[4];
    const float* W    = (const float*)d_in[5];
    const float* wrel = (const float*)d_in[6];
    const float* bias = (const float*)d_in[7];
    float* out = (float*)d_out;

    float* ws = (float*)d_ws;
    float*    sums   = ws + O_SUMS;
    float*    cnts   = ws + O_CNTS;
    int*      rowcnt = (int*)(ws + O_ROWCNT);
    unsigned* hkey   = (unsigned*)(ws + O_HKEY);
    unsigned* hprio  = (unsigned*)(ws + O_HPRIO);
    __bf16*   seqTp  = (__bf16*)(ws + O_SEQTP);
    float*    Nump   = ws + O_NUMP;
    float*    Sp     = ws + O_SP;
    uint2*    pairs  = (uint2*)(ws + O_PAIRS);

    int n4 = ZERO_WORDS / 4;
    k_zero<<<(n4 + 255) / 256, 256, 0, stream>>>((f32x4*)d_ws, n4);
    k_seqfts<<<NN / 16, 256, 0, stream>>>(x, W, seqTp);
    k_hash<<<(2 * EE + 255) / 256, 256, 0, stream>>>(ep, hkey, hprio);
    k_rel<<<RELBLK, 256, 0, stream>>>(rel, wrel, rseg, sums, cnts);
    k_main<<<NN / 16, 256, 0, stream>>>(adj, seqTp, Nump, Sp);
    k_scatB<<<(2 * EE + 255) / 256, 256, 0, stream>>>(ep, sums, cnts, hkey, hprio,
                                                      adj, rowcnt, pairs);
    k_rowupd<<<(NN + 3) / 4, 256, 0, stream>>>(Nump, Sp, rowcnt, pairs,
                                               seqTp, bias, out);
}